// Round 3
// baseline (569.451 us; speedup 1.0000x reference)
//
#include <hip/hip_runtime.h>
#include <hip/hip_bf16.h>
#include <hip/hip_cooperative_groups.h>

namespace cg = cooperative_groups;

typedef __attribute__((ext_vector_type(8))) short short8;   // 8 bf16 = 4 VGPRs (MFMA A/B frag)
typedef __attribute__((ext_vector_type(4))) float f32x4;    // MFMA C/D frag

#define MFMA(a, b, c) __builtin_amdgcn_mfma_f32_16x16x32_bf16((a), (b), (c), 0, 0, 0)

__device__ __forceinline__ unsigned short f2bf(float f) {
    unsigned int u = __float_as_uint(f);
    u += 0x7fffu + ((u >> 16) & 1u);          // round-to-nearest-even
    return (unsigned short)(u >> 16);
}

// pack two f32 -> one u32 of 2x bf16 (RNE), single instruction
__device__ __forceinline__ unsigned int cvt_pk_bf16(float lo, float hi) {
    unsigned int d;
    asm("v_cvt_pk_bf16_f32 %0, %1, %2" : "=v"(d) : "v"(lo), "v"(hi));
    return d;
}

// 16-lane sum via DPP row_ror (VALU-only). Each 16-lane row gets its full sum.
template<int CTRL>
__device__ __forceinline__ float dpp_addf(float v) {
    int t = __builtin_amdgcn_update_dpp(0, __float_as_int(v), CTRL, 0xF, 0xF, true);
    return v + __int_as_float(t);
}
__device__ __forceinline__ float rowsum16(float v) {
    v = dpp_addf<0x121>(v);   // row_ror:1
    v = dpp_addf<0x122>(v);   // row_ror:2
    v = dpp_addf<0x124>(v);   // row_ror:4
    v = dpp_addf<0x128>(v);   // row_ror:8
    return v;
}

#if __has_builtin(__builtin_amdgcn_exp2f)
#define EXP2(x) __builtin_amdgcn_exp2f(x)
#else
#define EXP2(x) __expf((x) * 0.69314718f)
#endif

// gelu tanh-form: x*E/(E+1) = x - x/(E+1), E=exp2(x*(2.3021210+0.10295427 x^2)).
// No clamp needed: E->inf => rcp->0 => x; E->0 => r->1 => 0. |err| <~3e-4.
__device__ __forceinline__ float gelu_fast(float x) {
    float a = x * __builtin_fmaf(x * x, 0.10295427f, 2.3021210f);
    float E = EXP2(a);
    float r = __builtin_amdgcn_rcpf(E + 1.0f);
    return __builtin_fmaf(-x, r, x);          // x*E/(E+1)
}

// B fragment from row-major [K][ldn] fp32 weight: r[u] = W[k0+u][n].
__device__ __forceinline__ short8 load_bfrag(const float* __restrict__ w, int k0, int n, int ldn) {
    short8 r;
#pragma unroll
    for (int u = 0; u < 8; ++u)
        r[u] = (short)f2bf(w[(k0 + u) * ldn + n]);
    return r;
}

template<int N1P>
struct SmemMlp {
    unsigned short sS[64 * N1P];     // union: A [64][K+8] then gelu(h) [64][N1P]
    float rstat[64 * 8];
};

// ---------------------------------------------------------------------------
// One MLP-head tile: out = gelu(LN(x@W1+b1)*g+be) @ W2 + b2 for MI*16 rows.
// 4 waves cooperative. breg1 resident, GEMM2 weights inline in a fully
// unrolled kk loop (compiler schedules loads early -> latency hidden; R2's
// "#pragma unroll 1" rolled version serialized on L2 latency, -4x).
// ---------------------------------------------------------------------------
template<int K, int N1, int N2, int MI>
__device__ void mlp_tile(SmemMlp<N1 + 8>& sm, const float* __restrict__ x,
                         const float* __restrict__ w1, const float* __restrict__ b1,
                         const float* __restrict__ g, const float* __restrict__ be,
                         const float* __restrict__ w2, const float* __restrict__ b2,
                         float* __restrict__ out, int Nrows, int t) {
    constexpr int R = MI * 16;                 // rows in this tile
    constexpr int KP = K + 8, N1P = N1 + 8;
    constexpr int CPW1 = N1 / 4;
    constexpr int JT1 = CPW1 / 16;
    constexpr int KK1 = K / 32;
    constexpr int KK2 = N1 / 32;
    constexpr int JT2 = N2 / 64;
    constexpr int TPR = 256 / R;               // threads per staged row
    constexpr int FPT = K / TPR;               // floats per thread
    constexpr int F4 = FPT / 4;

    const int tid = threadIdx.x;
    const int wave = tid >> 6, lane = tid & 63;
    const int l15 = lane & 15, quad = lane >> 4;
    const int r0 = t * R;

    __syncthreads();                           // smem reuse guard (prev tile done)
    {
        int m0 = tid / TPR, pp = tid % TPR;
        int rowg = r0 + m0; if (rowg >= Nrows) rowg = Nrows - 1;
        const float4* src = (const float4*)(x + (long)rowg * K + pp * FPT);
        unsigned short* dst = &sm.sS[m0 * KP + pp * FPT];
#pragma unroll
        for (int u = 0; u < F4; ++u) {
            float4 f = src[u];
            ushort4 h; h.x = f2bf(f.x); h.y = f2bf(f.y); h.z = f2bf(f.z); h.w = f2bf(f.w);
            *(ushort4*)(dst + 4 * u) = h;
        }
    }

    // resident W1 fragments + per-lane params (overlap with staging latency)
    short8 breg1[JT1][KK1];
#pragma unroll
    for (int j = 0; j < JT1; ++j)
#pragma unroll
        for (int kk = 0; kk < KK1; ++kk)
            breg1[j][kk] = load_bfrag(w1, kk * 32 + quad * 8, CPW1 * wave + 16 * j + l15, N1);

    float b1v[JT1], gv[JT1], bev[JT1];
#pragma unroll
    for (int j = 0; j < JT1; ++j) {
        int c = CPW1 * wave + 16 * j + l15;
        b1v[j] = b1[c]; gv[j] = g[c]; bev[j] = be[c];
    }
    float b2v[JT2];
#pragma unroll
    for (int j = 0; j < JT2; ++j) b2v[j] = b2[wave * 16 * JT2 + 16 * j + l15];

    __syncthreads();                           // A ready

    f32x4 acc1[MI][JT1];
#pragma unroll
    for (int i = 0; i < MI; ++i)
#pragma unroll
        for (int j = 0; j < JT1; ++j)
            acc1[i][j] = (f32x4){0.f, 0.f, 0.f, 0.f};

#pragma unroll
    for (int kk = 0; kk < KK1; ++kk) {
        short8 a[MI];
#pragma unroll
        for (int i = 0; i < MI; ++i)
            a[i] = *(const short8*)&sm.sS[(16 * i + l15) * KP + kk * 32 + quad * 8];
#pragma unroll
        for (int i = 0; i < MI; ++i)
#pragma unroll
            for (int j = 0; j < JT1; ++j)
                acc1[i][j] = MFMA(a[i], breg1[j][kk], acc1[i][j]);
    }

#pragma unroll
    for (int i = 0; i < MI; ++i)
#pragma unroll
        for (int r = 0; r < 4; ++r) {
            float s = 0.f, ss = 0.f;
#pragma unroll
            for (int j = 0; j < JT1; ++j) {
                float v = acc1[i][j][r] + b1v[j];
                acc1[i][j][r] = v;
                s += v; ss = __builtin_fmaf(v, v, ss);
            }
            s = rowsum16(s); ss = rowsum16(ss);
            if (l15 == 0) {
                int row = 16 * i + quad * 4 + r;
                *(float2*)&sm.rstat[row * 8 + wave * 2] = make_float2(s, ss);
            }
        }
    __syncthreads();                           // partials ready

#pragma unroll
    for (int i = 0; i < MI; ++i)
#pragma unroll
        for (int r = 0; r < 4; ++r) {
            int row = 16 * i + quad * 4 + r;
            const float4* st = (const float4*)&sm.rstat[row * 8];
            float4 q0 = st[0], q1 = st[1];
            float s  = (q0.x + q0.z) + (q1.x + q1.z);
            float ss = (q0.y + q0.w) + (q1.y + q1.w);
            float mean = s * (1.f / (float)N1);
            float var  = __builtin_fmaf(ss, 1.f / (float)N1, -mean * mean);
            float rstd = __builtin_amdgcn_rsqf(var + 1e-5f);
            float nm = -mean * rstd;
#pragma unroll
            for (int j = 0; j < JT1; ++j) {
                float tt = __builtin_fmaf(acc1[i][j][r], rstd, nm);
                float xn = __builtin_fmaf(tt, gv[j], bev[j]);
                sm.sS[row * N1P + CPW1 * wave + 16 * j + l15] = f2bf(gelu_fast(xn));
            }
        }
    __syncthreads();                           // gelu(h) ready in A-layout

    f32x4 acc2[MI][JT2];
#pragma unroll
    for (int i = 0; i < MI; ++i)
#pragma unroll
        for (int j = 0; j < JT2; ++j)
            acc2[i][j] = (f32x4){0.f, 0.f, 0.f, 0.f};

#pragma unroll
    for (int kk = 0; kk < KK2; ++kk) {
        short8 bf[JT2];
#pragma unroll
        for (int j = 0; j < JT2; ++j)
            bf[j] = load_bfrag(w2, kk * 32 + quad * 8, wave * 16 * JT2 + 16 * j + l15, N2);
        short8 a[MI];
#pragma unroll
        for (int i = 0; i < MI; ++i)
            a[i] = *(const short8*)&sm.sS[(16 * i + l15) * N1P + kk * 32 + quad * 8];
#pragma unroll
        for (int i = 0; i < MI; ++i)
#pragma unroll
            for (int j = 0; j < JT2; ++j)
                acc2[i][j] = MFMA(a[i], bf[j], acc2[i][j]);
    }

#pragma unroll
    for (int i = 0; i < MI; ++i)
#pragma unroll
        for (int r = 0; r < 4; ++r) {
            int rowg = r0 + 16 * i + quad * 4 + r;
            if (rowg < Nrows) {
#pragma unroll
                for (int j = 0; j < JT2; ++j)
                    out[(long)rowg * N2 + wave * 16 * JT2 + 16 * j + l15] = acc2[i][j][r] + b2v[j];
            }
        }
}

// ---------------------------------------------------------------------------
// One proj tile-plane: P = x @ W1half (+ b1 for A-plane), bf16 [N][256] in the
// PERMUTED column layout (storage slot wave*64+l15*4+j holds logical col
// wave*64+16*j+l15) -> one dwordx2 store per (i,r), fully contiguous.
// ---------------------------------------------------------------------------
__device__ void proj_tile(unsigned short* sX /*64*72*/, const float* __restrict__ x,
                          const float* __restrict__ w1, const float* __restrict__ b1,
                          unsigned short* __restrict__ P, int N, int tile, int isB) {
    constexpr int KP = 72;                     // 144B stride -> 2-way alias (free)
    const int tid = threadIdx.x;
    const int wave = tid >> 6, lane = tid & 63;
    const int l15 = lane & 15, quad = lane >> 4;
    const int r0 = tile * 64;

    __syncthreads();                           // smem reuse guard
    {
        int m0 = tid >> 2, pp = tid & 3;       // 4 threads/row, 16 floats each
        int rowg = r0 + m0; if (rowg >= N) rowg = N - 1;
        const float4* src = (const float4*)(x + (long)rowg * 64 + pp * 16);
        unsigned short* dst = &sX[m0 * KP + pp * 16];
#pragma unroll
        for (int u = 0; u < 4; ++u) {
            float4 f = src[u];
            ushort4 h; h.x = f2bf(f.x); h.y = f2bf(f.y); h.z = f2bf(f.z); h.w = f2bf(f.w);
            *(ushort4*)(dst + 4 * u) = h;
        }
    }

    short8 breg[4][2];
#pragma unroll
    for (int j = 0; j < 4; ++j)
#pragma unroll
        for (int kk = 0; kk < 2; ++kk)
            breg[j][kk] = load_bfrag(w1, isB * 64 + kk * 32 + quad * 8, wave * 64 + 16 * j + l15, 256);

    float b1v[4];
#pragma unroll
    for (int j = 0; j < 4; ++j)
        b1v[j] = isB ? 0.f : b1[wave * 64 + 16 * j + l15];

    __syncthreads();

    f32x4 acc[4][4];
#pragma unroll
    for (int i = 0; i < 4; ++i)
#pragma unroll
        for (int j = 0; j < 4; ++j)
            acc[i][j] = (f32x4){0.f, 0.f, 0.f, 0.f};

#pragma unroll
    for (int kk = 0; kk < 2; ++kk) {
        short8 a[4];
#pragma unroll
        for (int i = 0; i < 4; ++i)
            a[i] = *(const short8*)&sX[(16 * i + l15) * KP + kk * 32 + quad * 8];
#pragma unroll
        for (int i = 0; i < 4; ++i)
#pragma unroll
            for (int j = 0; j < 4; ++j)
                acc[i][j] = MFMA(a[i], breg[j][kk], acc[i][j]);
    }

#pragma unroll
    for (int i = 0; i < 4; ++i)
#pragma unroll
        for (int r = 0; r < 4; ++r) {
            int rowg = r0 + 16 * i + quad * 4 + r;     // C/D: row = quad*4+reg
            if (rowg < N) {
                uint2 d;
                d.x = cvt_pk_bf16(acc[i][0][r] + b1v[0], acc[i][1][r] + b1v[1]);
                d.y = cvt_pk_bf16(acc[i][2][r] + b1v[2], acc[i][3][r] + b1v[3]);
                *(uint2*)(P + (long)rowg * 256 + wave * 64 + l15 * 4) = d;
            }
        }
}

// ---------------------------------------------------------------------------
// Edge role: per wave 4 edges (one per 16-lane quad), 16 cols/lane.
// h = Pa[row] + Pb[col] in the proj-permuted layout; per-lane g/be/w2 params
// loaded with the matching permutation. 2-deep SW pipeline.
// ---------------------------------------------------------------------------
__device__ __forceinline__ int clamp_e(long v, int E) {
    return v < (long)E ? (int)v : E - 1;
}

__device__ void edge_role2(const unsigned short* __restrict__ Pa,
                           const unsigned short* __restrict__ Pb,
                           const int* __restrict__ ei,
                           const float* __restrict__ g, const float* __restrict__ be,
                           const float* __restrict__ w2, const float* __restrict__ b2,
                           float* __restrict__ out, int E, int ebid, int nebk) {
    const int tid = threadIdx.x;
    const int lane = tid & 63;
    const int quad = lane >> 4, l15 = lane & 15;

    // per-lane params for storage slots l15*16+u under the proj permutation:
    // logical col = (l15>>2)*64 + (u&3)*16 + (l15&3)*4 + (u>>2)
    float gv[16], bev[16], w2v[16];
#pragma unroll
    for (int u = 0; u < 16; ++u) {
        int c = ((l15 >> 2) << 6) + ((u & 3) << 4) + ((l15 & 3) << 2) + (u >> 2);
        gv[u] = g[c]; bev[u] = be[c]; w2v[u] = w2[c];
    }
    const float b2v = b2[0];

    const int wid = ebid * 4 + (tid >> 6);
    const long stride = (long)nebk * 16L;      // nebk blocks * 4 waves * 4 edges
    long base = (long)wid * 4;
    if (base >= E) return;

    // pipeline prologue: rows for iter 0, indices for iter 1
    int ir1, ic1;
    uint4 cA0, cA1, cB0, cB1;
    {
        int e0 = clamp_e(base + quad, E);
        int r = ei[e0], c = ei[E + e0];
        const uint4* pa = (const uint4*)(Pa + (long)r * 256 + l15 * 16);
        const uint4* pb = (const uint4*)(Pb + (long)c * 256 + l15 * 16);
        cA0 = pa[0]; cA1 = pa[1]; cB0 = pb[0]; cB1 = pb[1];
        int e1 = clamp_e(base + stride + quad, E);
        ir1 = ei[e1]; ic1 = ei[E + e1];
    }

    for (; base < E; base += stride) {
        int e2 = clamp_e(base + 2 * stride + quad, E);
        int ir2 = ei[e2];
        int ic2 = ei[E + e2];
        const uint4* pa = (const uint4*)(Pa + (long)ir1 * 256 + l15 * 16);
        const uint4* pb = (const uint4*)(Pb + (long)ic1 * 256 + l15 * 16);
        uint4 nA0 = pa[0], nA1 = pa[1], nB0 = pb[0], nB1 = pb[1];

        unsigned int av[8] = {cA0.x, cA0.y, cA0.z, cA0.w, cA1.x, cA1.y, cA1.z, cA1.w};
        unsigned int bv[8] = {cB0.x, cB0.y, cB0.z, cB0.w, cB1.x, cB1.y, cB1.z, cB1.w};

        float h[16];
#pragma unroll
        for (int k = 0; k < 8; ++k) {
            float alo = __uint_as_float(av[k] << 16);
            float ahi = __uint_as_float(av[k] & 0xffff0000u);
            float blo = __uint_as_float(bv[k] << 16);
            float bhi = __uint_as_float(bv[k] & 0xffff0000u);
            h[2*k]   = alo + blo;
            h[2*k+1] = ahi + bhi;
        }

        float s = 0.f, ss = 0.f;
#pragma unroll
        for (int u = 0; u < 16; ++u) {
            s += h[u];
            ss = __builtin_fmaf(h[u], h[u], ss);
        }
        s = rowsum16(s); ss = rowsum16(ss);

        float mean = s * (1.f / 256.f);
        float var  = __builtin_fmaf(ss, 1.f / 256.f, -mean * mean);
        float rstd = __builtin_amdgcn_rsqf(var + 1e-5f);
        float nm = -mean * rstd;

        float spp = 0.f;
#pragma unroll
        for (int u = 0; u < 16; ++u) {
            float tt = __builtin_fmaf(h[u], rstd, nm);
            float xn = __builtin_fmaf(tt, gv[u], bev[u]);
            spp = __builtin_fmaf(gelu_fast(xn), w2v[u], spp);
        }
        spp = rowsum16(spp);
        long eL = base + quad;
        if (l15 == 0 && eL < E) out[eL] = spp + b2v;

        cA0 = nA0; cA1 = nA1; cB0 = nB0; cB1 = nB1;
        ir1 = ir2; ic1 = ic2;
    }
}

union SmemCoop {
    unsigned short sX[64 * 72];
    SmemMlp<136> a;            // FR: N1=128
    SmemMlp<264> b;            // PH: N1=256 (35840 B, the max)
};

// ---------------------------------------------------------------------------
// coop_kernel: grid=1024 (4 blocks/CU @ <=128 VGPR, 35.8KB LDS), phases:
//   A: proj tile-planes (2*ntN tasks) spread over all blocks
//   grid.sync()  (edge gathers arbitrary Pa/Pb rows)
//   B: head tiles (nFR 64-row + nPH 32-row) spread over all blocks
//   C: every block rolls into the VALU-bound edge stream (no sync needed)
// ---------------------------------------------------------------------------
__global__ __launch_bounds__(256, 4)
void coop_kernel(const float* __restrict__ x, const int* __restrict__ ei,
                 const float* __restrict__ sp_w1, const float* __restrict__ sp_b1,
                 const float* __restrict__ sp_g, const float* __restrict__ sp_be,
                 const float* __restrict__ sp_w2, const float* __restrict__ sp_b2,
                 const float* __restrict__ fr_w1, const float* __restrict__ fr_b1,
                 const float* __restrict__ fr_g, const float* __restrict__ fr_be,
                 const float* __restrict__ fr_w2, const float* __restrict__ fr_b2,
                 const float* __restrict__ ph_w1, const float* __restrict__ ph_b1,
                 const float* __restrict__ ph_g, const float* __restrict__ ph_be,
                 const float* __restrict__ ph_w2, const float* __restrict__ ph_b2,
                 unsigned short* __restrict__ Pa, unsigned short* __restrict__ Pb,
                 float* __restrict__ out_sp, float* __restrict__ out_rec,
                 float* __restrict__ out_proj,
                 int N, int E, int ntN, int nFR, int nPH) {
    __shared__ SmemCoop sm;
    const int b = blockIdx.x;
    const int grid = gridDim.x;

    // Phase A: projection
    for (int q = b; q < 2 * ntN; q += grid) {
        int isB = q >= ntN;
        int tile = isB ? q - ntN : q;
        proj_tile(sm.sX, x, sp_w1, sp_b1, isB ? Pb : Pa, N, tile, isB);
    }

    __threadfence();
    cg::this_grid().sync();

    // Phase B: MLP heads
    const int nheads = nFR + nPH;
    for (int tt = b; tt < nheads; tt += grid) {
        if (tt < nFR)
            mlp_tile<64, 128, 64, 4>(sm.a, x, fr_w1, fr_b1, fr_g, fr_be, fr_w2, fr_b2,
                                     out_rec, N, tt);
        else
            mlp_tile<64, 256, 128, 2>(sm.b, x, ph_w1, ph_b1, ph_g, ph_be, ph_w2, ph_b2,
                                      out_proj, N, tt - nFR);
    }

    // Phase C: edge stream (starts as soon as this block's head share is done)
    edge_role2(Pa, Pb, ei, sp_g, sp_be, sp_w2, sp_b2, out_sp, E, b, grid);
}

// ===================== fallback path (coop launch refused) ==================
__global__ __launch_bounds__(256, 3)
void proj_kernel(const float* __restrict__ x, const float* __restrict__ w1,
                 const float* __restrict__ b1, unsigned short* __restrict__ Pa,
                 unsigned short* __restrict__ Pb, int N) {
    __shared__ unsigned short sX[64 * 72];
    for (int isB = 0; isB < 2; ++isB)
        proj_tile(sX, x, w1, b1, isB ? Pb : Pa, N, blockIdx.x, isB);
}

union SmemPrep {
    SmemMlp<136> a;
    SmemMlp<264> b;
};

__global__ __launch_bounds__(256, 4)
void fused_main(const float* __restrict__ x,
                const unsigned short* __restrict__ Pa, const unsigned short* __restrict__ Pb,
                const int* __restrict__ ei,
                const float* __restrict__ sp_g, const float* __restrict__ sp_be,
                const float* __restrict__ sp_w2, const float* __restrict__ sp_b2,
                const float* __restrict__ fr_w1, const float* __restrict__ fr_b1,
                const float* __restrict__ fr_g, const float* __restrict__ fr_be,
                const float* __restrict__ fr_w2, const float* __restrict__ fr_b2,
                const float* __restrict__ ph_w1, const float* __restrict__ ph_b1,
                const float* __restrict__ ph_g, const float* __restrict__ ph_be,
                const float* __restrict__ ph_w2, const float* __restrict__ ph_b2,
                float* __restrict__ out_sp, float* __restrict__ out_rec,
                float* __restrict__ out_proj, int N, int E, int nebk, int nFR, int nPH) {
    __shared__ SmemPrep sm;
    const int b = blockIdx.x;
    if (b < nebk) {
        edge_role2(Pa, Pb, ei, sp_g, sp_be, sp_w2, sp_b2, out_sp, E, b, nebk);
    } else {
        // heads distributed over 256 trailing blocks, tiles in time
        const int hb = b - nebk;
        const int nheads = nFR + nPH;
        for (int tt = hb; tt < nheads; tt += 256) {
            if (tt < nFR)
                mlp_tile<64, 128, 64, 4>(sm.a, x, fr_w1, fr_b1, fr_g, fr_be, fr_w2, fr_b2,
                                         out_rec, N, tt);
            else
                mlp_tile<64, 256, 128, 2>(sm.b, x, ph_w1, ph_b1, ph_g, ph_be, ph_w2, ph_b2,
                                          out_proj, N, tt - nFR);
        }
    }
}

// ======================= R6 fallback (ws too small) ==========================
struct SmemEdge {
    unsigned short sA[2][32 * 136];
    float rstat[32 * 8];
    float spL[32 * 4];
};
union SmemU {
    SmemEdge e;
    SmemMlp<136> a;
    SmemMlp<264> b;
};

__device__ void edge_role(SmemEdge& sm, const float* __restrict__ x, const int* __restrict__ ei,
                          const float* __restrict__ w1, const float* __restrict__ b1,
                          const float* __restrict__ g, const float* __restrict__ be,
                          const float* __restrict__ w2, const float* __restrict__ b2,
                          float* __restrict__ out, int E, int bid, int nblocks) {
    constexpr int KP = 136;
    const int tid = threadIdx.x;
    const int cw = tid >> 6, lane = tid & 63;
    const int l15 = lane & 15, quad = lane >> 4;

    short8 breg[4][4];
#pragma unroll
    for (int j = 0; j < 4; ++j)
#pragma unroll
        for (int kk = 0; kk < 4; ++kk)
            breg[j][kk] = load_bfrag(w1, kk * 32 + quad * 8, cw * 64 + 16 * j + l15, 256);

    float b1v[4], gv[4], bev[4], w2v[4];
#pragma unroll
    for (int j = 0; j < 4; ++j) {
        int c = cw * 64 + 16 * j + l15;
        b1v[j] = b1[c]; gv[j] = g[c]; bev[j] = be[c]; w2v[j] = w2[c];
    }
    const float b2v = b2[0];

    const int ntiles = (E + 31) >> 5;
    const int eLoc = tid >> 3, p = tid & 7;
    const int node = p >> 2, foff = (p & 3) * 16;

    float4 pf[4];
    auto issue = [&](int t) {
        int e = t * 32 + eLoc; if (e >= E) e = E - 1;
        int idx = ei[node * E + e];
        const float4* src = (const float4*)(x + (long)idx * 64 + foff);
#pragma unroll
        for (int u = 0; u < 4; ++u) pf[u] = src[u];
    };
    auto stage = [&](int buf) {
        unsigned short* dst = &sm.sA[buf][eLoc * KP + node * 64 + foff];
#pragma unroll
        for (int u = 0; u < 4; ++u) {
            ushort4 h;
            h.x = f2bf(pf[u].x); h.y = f2bf(pf[u].y);
            h.z = f2bf(pf[u].z); h.w = f2bf(pf[u].w);
            *(ushort4*)(dst + 4 * u) = h;
        }
    };

    int t = bid;
    if (t >= ntiles) return;
    issue(t); stage(0);
    if (t + nblocks < ntiles) issue(t + nblocks);
    __syncthreads();
    int cur = 0;

    for (; t < ntiles; t += nblocks) {
        f32x4 acc[2][4];
#pragma unroll
        for (int i = 0; i < 2; ++i)
#pragma unroll
            for (int j = 0; j < 4; ++j)
                acc[i][j] = (f32x4){0.f, 0.f, 0.f, 0.f};

#pragma unroll
        for (int kk = 0; kk < 4; ++kk) {
            short8 a[2];
#pragma unroll
            for (int i = 0; i < 2; ++i)
                a[i] = *(const short8*)&sm.sA[cur][(16 * i + l15) * KP + kk * 32 + quad * 8];
#pragma unroll
            for (int i = 0; i < 2; ++i)
#pragma unroll
                for (int j = 0; j < 4; ++j)
                    acc[i][j] = MFMA(a[i], breg[j][kk], acc[i][j]);
        }

        if (t + nblocks < ntiles) {
            stage(cur ^ 1);
            if (t + 2 * nblocks < ntiles) issue(t + 2 * nblocks);
        }

#pragma unroll
        for (int i = 0; i < 2; ++i)
#pragma unroll
            for (int r = 0; r < 4; ++r) {
                float v0 = acc[i][0][r] + b1v[0];
                float v1 = acc[i][1][r] + b1v[1];
                float v2 = acc[i][2][r] + b1v[2];
                float v3 = acc[i][3][r] + b1v[3];
                acc[i][0][r] = v0; acc[i][1][r] = v1; acc[i][2][r] = v2; acc[i][3][r] = v3;
                float s  = (v0 + v1) + (v2 + v3);
                float ss = __builtin_fmaf(v0, v0, __builtin_fmaf(v1, v1,
                           __builtin_fmaf(v2, v2, v3 * v3)));
                s = rowsum16(s); ss = rowsum16(ss);
                if (l15 == 0) {
                    int row = 16 * i + quad * 4 + r;
                    *(float2*)&sm.rstat[row * 8 + cw * 2] = make_float2(s, ss);
                }
            }
        __syncthreads();

#pragma unroll
        for (int i = 0; i < 2; ++i)
#pragma unroll
            for (int r = 0; r < 4; ++r) {
                int row = 16 * i + quad * 4 + r;
                const float4* st = (const float4*)&sm.rstat[row * 8];
                float4 q0 = st[0], q1 = st[1];
                float s  = (q0.x + q0.z) + (q1.x + q1.z);
                float ss = (q0.y + q0.w) + (q1.y + q1.w);
                float mean = s * (1.f / 256.f);
                float var  = __builtin_fmaf(ss, 1.f / 256.f, -mean * mean);
                float rstd = __builtin_amdgcn_rsqf(var + 1e-5f);
                float nm = -mean * rstd;
                float spp = 0.f;
#pragma unroll
                for (int j = 0; j < 4; ++j) {
                    float tt = __builtin_fmaf(acc[i][j][r], rstd, nm);
                    float xn = __builtin_fmaf(tt, gv[j], bev[j]);
                    spp = __builtin_fmaf(gelu_fast(xn), w2v[j], spp);
                }
                spp = rowsum16(spp);
                if (l15 == 0) sm.spL[row * 4 + cw] = spp;
            }
        __syncthreads();

        if (tid < 32) {
            int e = t * 32 + tid;
            if (e < E) {
                const float4* sp = (const float4*)&sm.spL[tid * 4];
                float4 u0 = sp[0];
                out[e] = ((u0.x + u0.y) + (u0.z + u0.w)) + b2v;
            }
        }
        cur ^= 1;
    }
}

__global__ __launch_bounds__(256, 3)
void fused_all(const float* __restrict__ x, const int* __restrict__ ei,
               const float* __restrict__ sp_w1, const float* __restrict__ sp_b1,
               const float* __restrict__ sp_g, const float* __restrict__ sp_be,
               const float* __restrict__ sp_w2, const float* __restrict__ sp_b2,
               const float* __restrict__ fr_w1, const float* __restrict__ fr_b1,
               const float* __restrict__ fr_g, const float* __restrict__ fr_be,
               const float* __restrict__ fr_w2, const float* __restrict__ fr_b2,
               const float* __restrict__ ph_w1, const float* __restrict__ ph_b1,
               const float* __restrict__ ph_g, const float* __restrict__ ph_be,
               const float* __restrict__ ph_w2, const float* __restrict__ ph_b2,
               float* __restrict__ out_sp, float* __restrict__ out_rec,
               float* __restrict__ out_proj, int N, int E) {
    __shared__ SmemU sm;
    const int b = blockIdx.x;
    if (b < 128) {
        for (int tt = b; tt < (N + 63) / 64; tt += 128)
            mlp_tile<64, 128, 64, 4>(sm.a, x, fr_w1, fr_b1, fr_g, fr_be, fr_w2, fr_b2,
                                     out_rec, N, tt);
    } else if (b < 256) {
        for (int tt = b - 128; tt < (N + 31) / 32; tt += 128)
            mlp_tile<64, 256, 128, 2>(sm.b, x, ph_w1, ph_b1, ph_g, ph_be, ph_w2, ph_b2,
                                      out_proj, N, tt);
    } else {
        edge_role(sm.e, x, ei, sp_w1, sp_b1, sp_g, sp_be, sp_w2, sp_b2,
                  out_sp, E, b - 256, 1024);
    }
}
// ===========================================================================

extern "C" void kernel_launch(void* const* d_in, const int* in_sizes, int n_in,
                              void* d_out, int out_size, void* d_ws, size_t ws_size,
                              hipStream_t stream) {
    const float* x     = (const float*)d_in[0];
    const int*   ei    = (const int*)d_in[1];
    const float* sp_w1 = (const float*)d_in[2];
    const float* sp_b1 = (const float*)d_in[3];
    const float* sp_g  = (const float*)d_in[4];
    const float* sp_be = (const float*)d_in[5];
    const float* sp_w2 = (const float*)d_in[6];
    const float* sp_b2 = (const float*)d_in[7];
    const float* fr_w1 = (const float*)d_in[8];
    const float* fr_b1 = (const float*)d_in[9];
    const float* fr_g  = (const float*)d_in[10];
    const float* fr_be = (const float*)d_in[11];
    const float* fr_w2 = (const float*)d_in[12];
    const float* fr_b2 = (const float*)d_in[13];
    const float* ph_w1 = (const float*)d_in[14];
    const float* ph_b1 = (const float*)d_in[15];
    const float* ph_g  = (const float*)d_in[16];
    const float* ph_be = (const float*)d_in[17];
    const float* ph_w2 = (const float*)d_in[18];
    const float* ph_b2 = (const float*)d_in[19];

    const int N = in_sizes[0] / 64;
    const int E = in_sizes[1] / 2;

    float* out_sp   = (float*)d_out;
    float* out_rec  = out_sp + E;
    float* out_proj = out_rec + (size_t)N * 64;

    const size_t needed = 2ull * (size_t)N * 256 * sizeof(unsigned short);
    if (ws_size >= needed) {
        unsigned short* Pa = (unsigned short*)d_ws;
        unsigned short* Pb = Pa + (size_t)N * 256;
        int ntN = (N + 63) / 64;
        int nFR = (N + 63) / 64;
        int nPH = (N + 31) / 32;

        void* args[] = {
            (void*)&x, (void*)&ei,
            (void*)&sp_w1, (void*)&sp_b1, (void*)&sp_g, (void*)&sp_be,
            (void*)&sp_w2, (void*)&sp_b2,
            (void*)&fr_w1, (void*)&fr_b1, (void*)&fr_g, (void*)&fr_be,
            (void*)&fr_w2, (void*)&fr_b2,
            (void*)&ph_w1, (void*)&ph_b1, (void*)&ph_g, (void*)&ph_be,
            (void*)&ph_w2, (void*)&ph_b2,
            (void*)&Pa, (void*)&Pb,
            (void*)&out_sp, (void*)&out_rec, (void*)&out_proj,
            (void*)&N, (void*)&E, (void*)&ntN, (void*)&nFR, (void*)&nPH};

        hipError_t ce = hipLaunchCooperativeKernel((const void*)coop_kernel,
                                                   dim3(1024), dim3(256),
                                                   args, 0, stream);
        if (ce != hipSuccess) {
            (void)hipGetLastError();           // clear sticky error
            const int NEB = 2048;
            proj_kernel<<<dim3(ntN), dim3(256), 0, stream>>>(x, sp_w1, sp_b1, Pa, Pb, N);
            fused_main<<<dim3(NEB + 256), dim3(256), 0, stream>>>(
                x, Pa, Pb, ei, sp_g, sp_be, sp_w2, sp_b2,
                fr_w1, fr_b1, fr_g, fr_be, fr_w2, fr_b2,
                ph_w1, ph_b1, ph_g, ph_be, ph_w2, ph_b2,
                out_sp, out_rec, out_proj, N, E, NEB, nFR, nPH);
        }
    } else {
        fused_all<<<dim3(1280), dim3(256), 0, stream>>>(
            x, ei, sp_w1, sp_b1, sp_g, sp_be, sp_w2, sp_b2,
            fr_w1, fr_b1, fr_g, fr_be, fr_w2, fr_b2,
            ph_w1, ph_b1, ph_g, ph_be, ph_w2, ph_b2,
            out_sp, out_rec, out_proj, N, E);
    }
}

// Round 4
// 273.790 us; speedup vs baseline: 2.0799x; 2.0799x over previous
//
#include <hip/hip_runtime.h>
#include <hip/hip_bf16.h>

typedef __attribute__((ext_vector_type(8))) short short8;   // 8 bf16 = 4 VGPRs (MFMA A/B frag)
typedef __attribute__((ext_vector_type(4))) float f32x4;    // MFMA C/D frag

#define MFMA(a, b, c) __builtin_amdgcn_mfma_f32_16x16x32_bf16((a), (b), (c), 0, 0, 0)

__device__ __forceinline__ unsigned short f2bf(float f) {
    unsigned int u = __float_as_uint(f);
    u += 0x7fffu + ((u >> 16) & 1u);          // round-to-nearest-even
    return (unsigned short)(u >> 16);
}

// pack two f32 -> one u32 of 2x bf16 (RNE), single instruction
__device__ __forceinline__ unsigned int cvt_pk_bf16(float lo, float hi) {
    unsigned int d;
    asm("v_cvt_pk_bf16_f32 %0, %1, %2" : "=v"(d) : "v"(lo), "v"(hi));
    return d;
}

// 16-lane sum via DPP row_ror (VALU-only). Each 16-lane row gets its full sum.
template<int CTRL>
__device__ __forceinline__ float dpp_addf(float v) {
    int t = __builtin_amdgcn_update_dpp(0, __float_as_int(v), CTRL, 0xF, 0xF, true);
    return v + __int_as_float(t);
}
__device__ __forceinline__ float rowsum16(float v) {
    v = dpp_addf<0x121>(v);   // row_ror:1
    v = dpp_addf<0x122>(v);   // row_ror:2
    v = dpp_addf<0x124>(v);   // row_ror:4
    v = dpp_addf<0x128>(v);   // row_ror:8
    return v;
}

#if __has_builtin(__builtin_amdgcn_exp2f)
#define EXP2(x) __builtin_amdgcn_exp2f(x)
#else
#define EXP2(x) __expf((x) * 0.69314718f)
#endif

// gelu tanh-form: x*E/(E+1) = x - x/(E+1), E=exp2(x*(2.3021210+0.10295427 x^2)).
// No clamp needed: E->inf => rcp->0 => x; E->0 => r->1 => 0. |err| <~3e-4.
__device__ __forceinline__ float gelu_fast(float x) {
    float a = x * __builtin_fmaf(x * x, 0.10295427f, 2.3021210f);
    float E = EXP2(a);
    float r = __builtin_amdgcn_rcpf(E + 1.0f);
    return __builtin_fmaf(-x, r, x);          // x*E/(E+1)
}

// B fragment from row-major [K][ldn] fp32 weight: r[u] = W[k0+u][n].
__device__ __forceinline__ short8 load_bfrag(const float* __restrict__ w, int k0, int n, int ldn) {
    short8 r;
#pragma unroll
    for (int u = 0; u < 8; ++u)
        r[u] = (short)f2bf(w[(k0 + u) * ldn + n]);
    return r;
}

template<int N1P>
struct SmemMlp {
    unsigned short sS[64 * N1P];     // union: A [64][K+8] then gelu(h) [64][N1P]
    float rstat[64 * 8];
};

// ---------------------------------------------------------------------------
// One MLP-head tile: out = gelu(LN(x@W1+b1)*g+be) @ W2 + b2 for MI*16 rows.
// 4 waves cooperative, fully unrolled, resident breg1. ONE tile per block
// (R4): R0's 6-tiles-serial-per-block made prep latency-bound (counters:
// all-idle during 149us).
// ---------------------------------------------------------------------------
template<int K, int N1, int N2, int MI>
__device__ void mlp_tile(SmemMlp<N1 + 8>& sm, const float* __restrict__ x,
                         const float* __restrict__ w1, const float* __restrict__ b1,
                         const float* __restrict__ g, const float* __restrict__ be,
                         const float* __restrict__ w2, const float* __restrict__ b2,
                         float* __restrict__ out, int Nrows, int t) {
    constexpr int R = MI * 16;                 // rows in this tile
    constexpr int KP = K + 8, N1P = N1 + 8;
    constexpr int CPW1 = N1 / 4;
    constexpr int JT1 = CPW1 / 16;
    constexpr int KK1 = K / 32;
    constexpr int KK2 = N1 / 32;
    constexpr int JT2 = N2 / 64;
    constexpr int TPR = 256 / R;               // threads per staged row
    constexpr int FPT = K / TPR;               // floats per thread
    constexpr int F4 = FPT / 4;

    const int tid = threadIdx.x;
    const int wave = tid >> 6, lane = tid & 63;
    const int l15 = lane & 15, quad = lane >> 4;
    const int r0 = t * R;

    {
        int m0 = tid / TPR, pp = tid % TPR;
        int rowg = r0 + m0; if (rowg >= Nrows) rowg = Nrows - 1;
        const float4* src = (const float4*)(x + (long)rowg * K + pp * FPT);
        unsigned short* dst = &sm.sS[m0 * KP + pp * FPT];
#pragma unroll
        for (int u = 0; u < F4; ++u) {
            float4 f = src[u];
            ushort4 h; h.x = f2bf(f.x); h.y = f2bf(f.y); h.z = f2bf(f.z); h.w = f2bf(f.w);
            *(ushort4*)(dst + 4 * u) = h;
        }
    }

    // resident W1 fragments + per-lane params (overlap with staging latency)
    short8 breg1[JT1][KK1];
#pragma unroll
    for (int j = 0; j < JT1; ++j)
#pragma unroll
        for (int kk = 0; kk < KK1; ++kk)
            breg1[j][kk] = load_bfrag(w1, kk * 32 + quad * 8, CPW1 * wave + 16 * j + l15, N1);

    float b1v[JT1], gv[JT1], bev[JT1];
#pragma unroll
    for (int j = 0; j < JT1; ++j) {
        int c = CPW1 * wave + 16 * j + l15;
        b1v[j] = b1[c]; gv[j] = g[c]; bev[j] = be[c];
    }
    float b2v[JT2];
#pragma unroll
    for (int j = 0; j < JT2; ++j) b2v[j] = b2[wave * 16 * JT2 + 16 * j + l15];

    __syncthreads();                           // A ready

    f32x4 acc1[MI][JT1];
#pragma unroll
    for (int i = 0; i < MI; ++i)
#pragma unroll
        for (int j = 0; j < JT1; ++j)
            acc1[i][j] = (f32x4){0.f, 0.f, 0.f, 0.f};

#pragma unroll
    for (int kk = 0; kk < KK1; ++kk) {
        short8 a[MI];
#pragma unroll
        for (int i = 0; i < MI; ++i)
            a[i] = *(const short8*)&sm.sS[(16 * i + l15) * KP + kk * 32 + quad * 8];
#pragma unroll
        for (int i = 0; i < MI; ++i)
#pragma unroll
            for (int j = 0; j < JT1; ++j)
                acc1[i][j] = MFMA(a[i], breg1[j][kk], acc1[i][j]);
    }

#pragma unroll
    for (int i = 0; i < MI; ++i)
#pragma unroll
        for (int r = 0; r < 4; ++r) {
            float s = 0.f, ss = 0.f;
#pragma unroll
            for (int j = 0; j < JT1; ++j) {
                float v = acc1[i][j][r] + b1v[j];
                acc1[i][j][r] = v;
                s += v; ss = __builtin_fmaf(v, v, ss);
            }
            s = rowsum16(s); ss = rowsum16(ss);
            if (l15 == 0) {
                int row = 16 * i + quad * 4 + r;
                *(float2*)&sm.rstat[row * 8 + wave * 2] = make_float2(s, ss);
            }
        }
    __syncthreads();                           // partials ready

#pragma unroll
    for (int i = 0; i < MI; ++i)
#pragma unroll
        for (int r = 0; r < 4; ++r) {
            int row = 16 * i + quad * 4 + r;
            const float4* st = (const float4*)&sm.rstat[row * 8];
            float4 q0 = st[0], q1 = st[1];
            float s  = (q0.x + q0.z) + (q1.x + q1.z);
            float ss = (q0.y + q0.w) + (q1.y + q1.w);
            float mean = s * (1.f / (float)N1);
            float var  = __builtin_fmaf(ss, 1.f / (float)N1, -mean * mean);
            float rstd = __builtin_amdgcn_rsqf(var + 1e-5f);
            float nm = -mean * rstd;
#pragma unroll
            for (int j = 0; j < JT1; ++j) {
                float tt = __builtin_fmaf(acc1[i][j][r], rstd, nm);
                float xn = __builtin_fmaf(tt, gv[j], bev[j]);
                sm.sS[row * N1P + CPW1 * wave + 16 * j + l15] = f2bf(gelu_fast(xn));
            }
        }
    __syncthreads();                           // gelu(h) ready in A-layout

    f32x4 acc2[MI][JT2];
#pragma unroll
    for (int i = 0; i < MI; ++i)
#pragma unroll
        for (int j = 0; j < JT2; ++j)
            acc2[i][j] = (f32x4){0.f, 0.f, 0.f, 0.f};

#pragma unroll
    for (int kk = 0; kk < KK2; ++kk) {
        short8 bf[JT2];
#pragma unroll
        for (int j = 0; j < JT2; ++j)
            bf[j] = load_bfrag(w2, kk * 32 + quad * 8, wave * 16 * JT2 + 16 * j + l15, N2);
        short8 a[MI];
#pragma unroll
        for (int i = 0; i < MI; ++i)
            a[i] = *(const short8*)&sm.sS[(16 * i + l15) * N1P + kk * 32 + quad * 8];
#pragma unroll
        for (int i = 0; i < MI; ++i)
#pragma unroll
            for (int j = 0; j < JT2; ++j)
                acc2[i][j] = MFMA(a[i], bf[j], acc2[i][j]);
    }

#pragma unroll
    for (int i = 0; i < MI; ++i)
#pragma unroll
        for (int r = 0; r < 4; ++r) {
            int rowg = r0 + 16 * i + quad * 4 + r;
            if (rowg < Nrows) {
#pragma unroll
                for (int j = 0; j < JT2; ++j)
                    out[(long)rowg * N2 + wave * 16 * JT2 + 16 * j + l15] = acc2[i][j][r] + b2v[j];
            }
        }
}

// ---------------------------------------------------------------------------
// One proj tile-plane: P = x @ W1half (+ b1 for A-plane), bf16 [N][256] in the
// PERMUTED column layout (storage slot wave*64+l15*4+j holds logical col
// wave*64+16*j+l15) -> one dwordx2 store per (i,r), fully contiguous.
// ---------------------------------------------------------------------------
__device__ void proj_tile(unsigned short* sX /*64*72*/, const float* __restrict__ x,
                          const float* __restrict__ w1, const float* __restrict__ b1,
                          unsigned short* __restrict__ P, int N, int tile, int isB) {
    constexpr int KP = 72;                     // 144B stride -> 2-way alias (free)
    const int tid = threadIdx.x;
    const int wave = tid >> 6, lane = tid & 63;
    const int l15 = lane & 15, quad = lane >> 4;
    const int r0 = tile * 64;

    {
        int m0 = tid >> 2, pp = tid & 3;       // 4 threads/row, 16 floats each
        int rowg = r0 + m0; if (rowg >= N) rowg = N - 1;
        const float4* src = (const float4*)(x + (long)rowg * 64 + pp * 16);
        unsigned short* dst = &sX[m0 * KP + pp * 16];
#pragma unroll
        for (int u = 0; u < 4; ++u) {
            float4 f = src[u];
            ushort4 h; h.x = f2bf(f.x); h.y = f2bf(f.y); h.z = f2bf(f.z); h.w = f2bf(f.w);
            *(ushort4*)(dst + 4 * u) = h;
        }
    }

    short8 breg[4][2];
#pragma unroll
    for (int j = 0; j < 4; ++j)
#pragma unroll
        for (int kk = 0; kk < 2; ++kk)
            breg[j][kk] = load_bfrag(w1, isB * 64 + kk * 32 + quad * 8, wave * 64 + 16 * j + l15, 256);

    float b1v[4];
#pragma unroll
    for (int j = 0; j < 4; ++j)
        b1v[j] = isB ? 0.f : b1[wave * 64 + 16 * j + l15];

    __syncthreads();

    f32x4 acc[4][4];
#pragma unroll
    for (int i = 0; i < 4; ++i)
#pragma unroll
        for (int j = 0; j < 4; ++j)
            acc[i][j] = (f32x4){0.f, 0.f, 0.f, 0.f};

#pragma unroll
    for (int kk = 0; kk < 2; ++kk) {
        short8 a[4];
#pragma unroll
        for (int i = 0; i < 4; ++i)
            a[i] = *(const short8*)&sX[(16 * i + l15) * KP + kk * 32 + quad * 8];
#pragma unroll
        for (int i = 0; i < 4; ++i)
#pragma unroll
            for (int j = 0; j < 4; ++j)
                acc[i][j] = MFMA(a[i], breg[j][kk], acc[i][j]);
    }

#pragma unroll
    for (int i = 0; i < 4; ++i)
#pragma unroll
        for (int r = 0; r < 4; ++r) {
            int rowg = r0 + 16 * i + quad * 4 + r;     // C/D: row = quad*4+reg
            if (rowg < N) {
                uint2 d;
                d.x = cvt_pk_bf16(acc[i][0][r] + b1v[0], acc[i][1][r] + b1v[1]);
                d.y = cvt_pk_bf16(acc[i][2][r] + b1v[2], acc[i][3][r] + b1v[3]);
                *(uint2*)(P + (long)rowg * 256 + wave * 64 + l15 * 4) = d;
            }
        }
}

// ---------------------------------------------------------------------------
// Edge role: per wave 4 edges (one per 16-lane quad), 16 cols/lane.
// h = Pa[row] + Pb[col] in the proj-permuted layout; per-lane g/be/w2 params
// loaded with the matching permutation. 2-deep SW pipeline.
// ---------------------------------------------------------------------------
__device__ __forceinline__ int clamp_e(long v, int E) {
    return v < (long)E ? (int)v : E - 1;
}

__device__ void edge_role2(const unsigned short* __restrict__ Pa,
                           const unsigned short* __restrict__ Pb,
                           const int* __restrict__ ei,
                           const float* __restrict__ g, const float* __restrict__ be,
                           const float* __restrict__ w2, const float* __restrict__ b2,
                           float* __restrict__ out, int E, int ebid, int nebk) {
    const int tid = threadIdx.x;
    const int lane = tid & 63;
    const int quad = lane >> 4, l15 = lane & 15;

    // per-lane params for storage slots l15*16+u under the proj permutation:
    // logical col = (l15>>2)*64 + (u&3)*16 + (l15&3)*4 + (u>>2)
    float gv[16], bev[16], w2v[16];
#pragma unroll
    for (int u = 0; u < 16; ++u) {
        int c = ((l15 >> 2) << 6) + ((u & 3) << 4) + ((l15 & 3) << 2) + (u >> 2);
        gv[u] = g[c]; bev[u] = be[c]; w2v[u] = w2[c];
    }
    const float b2v = b2[0];

    const int wid = ebid * 4 + (tid >> 6);
    const long stride = (long)nebk * 16L;      // nebk blocks * 4 waves * 4 edges
    long base = (long)wid * 4;
    if (base >= E) return;

    // pipeline prologue: rows for iter 0, indices for iter 1
    int ir1, ic1;
    uint4 cA0, cA1, cB0, cB1;
    {
        int e0 = clamp_e(base + quad, E);
        int r = ei[e0], c = ei[E + e0];
        const uint4* pa = (const uint4*)(Pa + (long)r * 256 + l15 * 16);
        const uint4* pb = (const uint4*)(Pb + (long)c * 256 + l15 * 16);
        cA0 = pa[0]; cA1 = pa[1]; cB0 = pb[0]; cB1 = pb[1];
        int e1 = clamp_e(base + stride + quad, E);
        ir1 = ei[e1]; ic1 = ei[E + e1];
    }

    for (; base < E; base += stride) {
        int e2 = clamp_e(base + 2 * stride + quad, E);
        int ir2 = ei[e2];
        int ic2 = ei[E + e2];
        const uint4* pa = (const uint4*)(Pa + (long)ir1 * 256 + l15 * 16);
        const uint4* pb = (const uint4*)(Pb + (long)ic1 * 256 + l15 * 16);
        uint4 nA0 = pa[0], nA1 = pa[1], nB0 = pb[0], nB1 = pb[1];

        unsigned int av[8] = {cA0.x, cA0.y, cA0.z, cA0.w, cA1.x, cA1.y, cA1.z, cA1.w};
        unsigned int bv[8] = {cB0.x, cB0.y, cB0.z, cB0.w, cB1.x, cB1.y, cB1.z, cB1.w};

        float h[16];
#pragma unroll
        for (int k = 0; k < 8; ++k) {
            float alo = __uint_as_float(av[k] << 16);
            float ahi = __uint_as_float(av[k] & 0xffff0000u);
            float blo = __uint_as_float(bv[k] << 16);
            float bhi = __uint_as_float(bv[k] & 0xffff0000u);
            h[2*k]   = alo + blo;
            h[2*k+1] = ahi + bhi;
        }

        float s = 0.f, ss = 0.f;
#pragma unroll
        for (int u = 0; u < 16; ++u) {
            s += h[u];
            ss = __builtin_fmaf(h[u], h[u], ss);
        }
        s = rowsum16(s); ss = rowsum16(ss);

        float mean = s * (1.f / 256.f);
        float var  = __builtin_fmaf(ss, 1.f / 256.f, -mean * mean);
        float rstd = __builtin_amdgcn_rsqf(var + 1e-5f);
        float nm = -mean * rstd;

        float spp = 0.f;
#pragma unroll
        for (int u = 0; u < 16; ++u) {
            float tt = __builtin_fmaf(h[u], rstd, nm);
            float xn = __builtin_fmaf(tt, gv[u], bev[u]);
            spp = __builtin_fmaf(gelu_fast(xn), w2v[u], spp);
        }
        spp = rowsum16(spp);
        long eL = base + quad;
        if (l15 == 0 && eL < E) out[eL] = spp + b2v;

        cA0 = nA0; cA1 = nA1; cB0 = nB0; cB1 = nB1;
        ir1 = ir2; ic1 = ic2;
    }
}

// =============================== R4 kernels =================================
// proj: one 64-row plane-tile per block, grid = 2*ntN.
__global__ __launch_bounds__(256, 3)
void proj_kernel(const float* __restrict__ x, const float* __restrict__ w1,
                 const float* __restrict__ b1, unsigned short* __restrict__ Pa,
                 unsigned short* __restrict__ Pb, int N, int ntN) {
    __shared__ unsigned short sX[64 * 72];
    const int q = blockIdx.x;
    const int isB = q >= ntN;
    const int tile = isB ? q - ntN : q;
    proj_tile(sX, x, w1, b1, isB ? Pb : Pa, N, tile, isB);
}

union SmemHeads {
    SmemMlp<136> a;            // FR: N1=128
    SmemMlp<264> b;            // PH: N1=256 (35840 B, the max)
};

// heads: one tile per block. Blocks [0,nFR) are FR 64-row tiles (MI=4);
// blocks [nFR, nFR+nPH) are PH 32-row tiles (MI=2, lower VGPR).
__global__ __launch_bounds__(256, 3)
void heads_kernel(const float* __restrict__ x,
                  const float* __restrict__ fr_w1, const float* __restrict__ fr_b1,
                  const float* __restrict__ fr_g, const float* __restrict__ fr_be,
                  const float* __restrict__ fr_w2, const float* __restrict__ fr_b2,
                  const float* __restrict__ ph_w1, const float* __restrict__ ph_b1,
                  const float* __restrict__ ph_g, const float* __restrict__ ph_be,
                  const float* __restrict__ ph_w2, const float* __restrict__ ph_b2,
                  float* __restrict__ out_rec, float* __restrict__ out_proj,
                  int N, int nFR) {
    __shared__ SmemHeads sm;
    const int b = blockIdx.x;
    if (b < nFR)
        mlp_tile<64, 128, 64, 4>(sm.a, x, fr_w1, fr_b1, fr_g, fr_be, fr_w2, fr_b2,
                                 out_rec, N, b);
    else
        mlp_tile<64, 256, 128, 2>(sm.b, x, ph_w1, ph_b1, ph_g, ph_be, ph_w2, ph_b2,
                                  out_proj, N, b - nFR);
}

// edge: standalone, 48-VGPR class, no LDS -- the proven 87%-VALUBusy config.
__global__ __launch_bounds__(256)
void edge_stream(const unsigned short* __restrict__ Pa, const unsigned short* __restrict__ Pb,
                 const int* __restrict__ ei,
                 const float* __restrict__ g, const float* __restrict__ be,
                 const float* __restrict__ w2, const float* __restrict__ b2,
                 float* __restrict__ out, int E) {
    edge_role2(Pa, Pb, ei, g, be, w2, b2, out, E, blockIdx.x, gridDim.x);
}

// ======================= fallback (ws too small) ============================
struct SmemEdge {
    unsigned short sA[2][32 * 136];
    float rstat[32 * 8];
    float spL[32 * 4];
};
union SmemU {
    SmemEdge e;
    SmemMlp<136> a;
    SmemMlp<264> b;
};

__device__ void edge_role(SmemEdge& sm, const float* __restrict__ x, const int* __restrict__ ei,
                          const float* __restrict__ w1, const float* __restrict__ b1,
                          const float* __restrict__ g, const float* __restrict__ be,
                          const float* __restrict__ w2, const float* __restrict__ b2,
                          float* __restrict__ out, int E, int bid, int nblocks) {
    constexpr int KP = 136;
    const int tid = threadIdx.x;
    const int cw = tid >> 6, lane = tid & 63;
    const int l15 = lane & 15, quad = lane >> 4;

    short8 breg[4][4];
#pragma unroll
    for (int j = 0; j < 4; ++j)
#pragma unroll
        for (int kk = 0; kk < 4; ++kk)
            breg[j][kk] = load_bfrag(w1, kk * 32 + quad * 8, cw * 64 + 16 * j + l15, 256);

    float b1v[4], gv[4], bev[4], w2v[4];
#pragma unroll
    for (int j = 0; j < 4; ++j) {
        int c = cw * 64 + 16 * j + l15;
        b1v[j] = b1[c]; gv[j] = g[c]; bev[j] = be[c]; w2v[j] = w2[c];
    }
    const float b2v = b2[0];

    const int ntiles = (E + 31) >> 5;
    const int eLoc = tid >> 3, p = tid & 7;
    const int node = p >> 2, foff = (p & 3) * 16;

    float4 pf[4];
    auto issue = [&](int t) {
        int e = t * 32 + eLoc; if (e >= E) e = E - 1;
        int idx = ei[node * E + e];
        const float4* src = (const float4*)(x + (long)idx * 64 + foff);
#pragma unroll
        for (int u = 0; u < 4; ++u) pf[u] = src[u];
    };
    auto stage = [&](int buf) {
        unsigned short* dst = &sm.sA[buf][eLoc * KP + node * 64 + foff];
#pragma unroll
        for (int u = 0; u < 4; ++u) {
            ushort4 h;
            h.x = f2bf(pf[u].x); h.y = f2bf(pf[u].y);
            h.z = f2bf(pf[u].z); h.w = f2bf(pf[u].w);
            *(ushort4*)(dst + 4 * u) = h;
        }
    };

    int t = bid;
    if (t >= ntiles) return;
    issue(t); stage(0);
    if (t + nblocks < ntiles) issue(t + nblocks);
    __syncthreads();
    int cur = 0;

    for (; t < ntiles; t += nblocks) {
        f32x4 acc[2][4];
#pragma unroll
        for (int i = 0; i < 2; ++i)
#pragma unroll
            for (int j = 0; j < 4; ++j)
                acc[i][j] = (f32x4){0.f, 0.f, 0.f, 0.f};

#pragma unroll
        for (int kk = 0; kk < 4; ++kk) {
            short8 a[2];
#pragma unroll
            for (int i = 0; i < 2; ++i)
                a[i] = *(const short8*)&sm.sA[cur][(16 * i + l15) * KP + kk * 32 + quad * 8];
#pragma unroll
            for (int i = 0; i < 2; ++i)
#pragma unroll
                for (int j = 0; j < 4; ++j)
                    acc[i][j] = MFMA(a[i], breg[j][kk], acc[i][j]);
        }

        if (t + nblocks < ntiles) {
            stage(cur ^ 1);
            if (t + 2 * nblocks < ntiles) issue(t + 2 * nblocks);
        }

#pragma unroll
        for (int i = 0; i < 2; ++i)
#pragma unroll
            for (int r = 0; r < 4; ++r) {
                float v0 = acc[i][0][r] + b1v[0];
                float v1 = acc[i][1][r] + b1v[1];
                float v2 = acc[i][2][r] + b1v[2];
                float v3 = acc[i][3][r] + b1v[3];
                acc[i][0][r] = v0; acc[i][1][r] = v1; acc[i][2][r] = v2; acc[i][3][r] = v3;
                float s  = (v0 + v1) + (v2 + v3);
                float ss = __builtin_fmaf(v0, v0, __builtin_fmaf(v1, v1,
                           __builtin_fmaf(v2, v2, v3 * v3)));
                s = rowsum16(s); ss = rowsum16(ss);
                if (l15 == 0) {
                    int row = 16 * i + quad * 4 + r;
                    *(float2*)&sm.rstat[row * 8 + cw * 2] = make_float2(s, ss);
                }
            }
        __syncthreads();

#pragma unroll
        for (int i = 0; i < 2; ++i)
#pragma unroll
            for (int r = 0; r < 4; ++r) {
                int row = 16 * i + quad * 4 + r;
                const float4* st = (const float4*)&sm.rstat[row * 8];
                float4 q0 = st[0], q1 = st[1];
                float s  = (q0.x + q0.z) + (q1.x + q1.z);
                float ss = (q0.y + q0.w) + (q1.y + q1.w);
                float mean = s * (1.f / 256.f);
                float var  = __builtin_fmaf(ss, 1.f / 256.f, -mean * mean);
                float rstd = __builtin_amdgcn_rsqf(var + 1e-5f);
                float nm = -mean * rstd;
                float spp = 0.f;
#pragma unroll
                for (int j = 0; j < 4; ++j) {
                    float tt = __builtin_fmaf(acc[i][j][r], rstd, nm);
                    float xn = __builtin_fmaf(tt, gv[j], bev[j]);
                    spp = __builtin_fmaf(gelu_fast(xn), w2v[j], spp);
                }
                spp = rowsum16(spp);
                if (l15 == 0) sm.spL[row * 4 + cw] = spp;
            }
        __syncthreads();

        if (tid < 32) {
            int e = t * 32 + tid;
            if (e < E) {
                const float4* sp = (const float4*)&sm.spL[tid * 4];
                float4 u0 = sp[0];
                out[e] = ((u0.x + u0.y) + (u0.z + u0.w)) + b2v;
            }
        }
        cur ^= 1;
    }
}

__global__ __launch_bounds__(256, 3)
void fused_all(const float* __restrict__ x, const int* __restrict__ ei,
               const float* __restrict__ sp_w1, const float* __restrict__ sp_b1,
               const float* __restrict__ sp_g, const float* __restrict__ sp_be,
               const float* __restrict__ sp_w2, const float* __restrict__ sp_b2,
               const float* __restrict__ fr_w1, const float* __restrict__ fr_b1,
               const float* __restrict__ fr_g, const float* __restrict__ fr_be,
               const float* __restrict__ fr_w2, const float* __restrict__ fr_b2,
               const float* __restrict__ ph_w1, const float* __restrict__ ph_b1,
               const float* __restrict__ ph_g, const float* __restrict__ ph_be,
               const float* __restrict__ ph_w2, const float* __restrict__ ph_b2,
               float* __restrict__ out_sp, float* __restrict__ out_rec,
               float* __restrict__ out_proj, int N, int E) {
    __shared__ SmemU sm;
    const int b = blockIdx.x;
    if (b < 128) {
        for (int tt = b; tt < (N + 63) / 64; tt += 128)
            mlp_tile<64, 128, 64, 4>(sm.a, x, fr_w1, fr_b1, fr_g, fr_be, fr_w2, fr_b2,
                                     out_rec, N, tt);
    } else if (b < 256) {
        for (int tt = b - 128; tt < (N + 31) / 32; tt += 128)
            mlp_tile<64, 256, 128, 2>(sm.b, x, ph_w1, ph_b1, ph_g, ph_be, ph_w2, ph_b2,
                                      out_proj, N, tt);
    } else {
        edge_role(sm.e, x, ei, sp_w1, sp_b1, sp_g, sp_be, sp_w2, sp_b2,
                  out_sp, E, b - 256, 1024);
    }
}
// ===========================================================================

extern "C" void kernel_launch(void* const* d_in, const int* in_sizes, int n_in,
                              void* d_out, int out_size, void* d_ws, size_t ws_size,
                              hipStream_t stream) {
    const float* x     = (const float*)d_in[0];
    const int*   ei    = (const int*)d_in[1];
    const float* sp_w1 = (const float*)d_in[2];
    const float* sp_b1 = (const float*)d_in[3];
    const float* sp_g  = (const float*)d_in[4];
    const float* sp_be = (const float*)d_in[5];
    const float* sp_w2 = (const float*)d_in[6];
    const float* sp_b2 = (const float*)d_in[7];
    const float* fr_w1 = (const float*)d_in[8];
    const float* fr_b1 = (const float*)d_in[9];
    const float* fr_g  = (const float*)d_in[10];
    const float* fr_be = (const float*)d_in[11];
    const float* fr_w2 = (const float*)d_in[12];
    const float* fr_b2 = (const float*)d_in[13];
    const float* ph_w1 = (const float*)d_in[14];
    const float* ph_b1 = (const float*)d_in[15];
    const float* ph_g  = (const float*)d_in[16];
    const float* ph_be = (const float*)d_in[17];
    const float* ph_w2 = (const float*)d_in[18];
    const float* ph_b2 = (const float*)d_in[19];

    const int N = in_sizes[0] / 64;
    const int E = in_sizes[1] / 2;

    float* out_sp   = (float*)d_out;
    float* out_rec  = out_sp + E;
    float* out_proj = out_rec + (size_t)N * 64;

    const size_t needed = 2ull * (size_t)N * 256 * sizeof(unsigned short);
    if (ws_size >= needed) {
        unsigned short* Pa = (unsigned short*)d_ws;
        unsigned short* Pb = Pa + (size_t)N * 256;
        const int ntN = (N + 63) / 64;         // proj tiles per plane
        const int nFR = (N + 63) / 64;         // FR tiles (64-row)
        const int nPH = (N + 31) / 32;         // PH tiles (32-row)

        proj_kernel<<<dim3(2 * ntN), dim3(256), 0, stream>>>(
            x, sp_w1, sp_b1, Pa, Pb, N, ntN);

        heads_kernel<<<dim3(nFR + nPH), dim3(256), 0, stream>>>(
            x, fr_w1, fr_b1, fr_g, fr_be, fr_w2, fr_b2,
            ph_w1, ph_b1, ph_g, ph_be, ph_w2, ph_b2,
            out_rec, out_proj, N, nFR);

        edge_stream<<<dim3(2048), dim3(256), 0, stream>>>(
            Pa, Pb, ei, sp_g, sp_be, sp_w2, sp_b2, out_sp, E);
    } else {
        fused_all<<<dim3(1280), dim3(256), 0, stream>>>(
            x, ei, sp_w1, sp_b1, sp_g, sp_be, sp_w2, sp_b2,
            fr_w1, fr_b1, fr_g, fr_be, fr_w2, fr_b2,
            ph_w1, ph_b1, ph_g, ph_be, ph_w2, ph_b2,
            out_sp, out_rec, out_proj, N, E);
    }
}

// Round 5
// 259.821 us; speedup vs baseline: 2.1917x; 1.0538x over previous
//
#include <hip/hip_runtime.h>
#include <hip/hip_bf16.h>

typedef __attribute__((ext_vector_type(8))) short short8;   // 8 bf16 = 4 VGPRs (MFMA A/B frag)
typedef __attribute__((ext_vector_type(4))) float f32x4;    // MFMA C/D frag
typedef __attribute__((ext_vector_type(2))) float f32x2;    // packed-f32 (v_pk_*) pair

#define MFMA(a, b, c) __builtin_amdgcn_mfma_f32_16x16x32_bf16((a), (b), (c), 0, 0, 0)

__device__ __forceinline__ unsigned short f2bf(float f) {
    unsigned int u = __float_as_uint(f);
    u += 0x7fffu + ((u >> 16) & 1u);          // round-to-nearest-even
    return (unsigned short)(u >> 16);
}

// pack two f32 -> one u32 of 2x bf16 (RNE), single instruction
__device__ __forceinline__ unsigned int cvt_pk_bf16(float lo, float hi) {
    unsigned int d;
    asm("v_cvt_pk_bf16_f32 %0, %1, %2" : "=v"(d) : "v"(lo), "v"(hi));
    return d;
}

// 16-lane sum via DPP row_ror (VALU-only). Each 16-lane row gets its full sum.
template<int CTRL>
__device__ __forceinline__ float dpp_addf(float v) {
    int t = __builtin_amdgcn_update_dpp(0, __float_as_int(v), CTRL, 0xF, 0xF, true);
    return v + __int_as_float(t);
}
__device__ __forceinline__ float rowsum16(float v) {
    v = dpp_addf<0x121>(v);   // row_ror:1
    v = dpp_addf<0x122>(v);   // row_ror:2
    v = dpp_addf<0x124>(v);   // row_ror:4
    v = dpp_addf<0x128>(v);   // row_ror:8
    return v;
}

#if __has_builtin(__builtin_amdgcn_exp2f)
#define EXP2(x) __builtin_amdgcn_exp2f(x)
#else
#define EXP2(x) __expf((x) * 0.69314718f)
#endif

// gelu tanh-form: x*E/(E+1) = x - x/(E+1), E=exp2(x*(2.3021210+0.10295427 x^2)).
// No clamp needed: E->inf => rcp->0 => x; E->0 => r->1 => 0. |err| <~3e-4.
__device__ __forceinline__ float gelu_fast(float x) {
    float a = x * __builtin_fmaf(x * x, 0.10295427f, 2.3021210f);
    float E = EXP2(a);
    float r = __builtin_amdgcn_rcpf(E + 1.0f);
    return __builtin_fmaf(-x, r, x);          // x*E/(E+1)
}

// packed (2-wide) gelu: elementwise ops vectorized so backend can emit
// v_pk_mul/v_pk_add/v_pk_fma; exp2/rcp remain scalar trans ops.
__device__ __forceinline__ f32x2 gelu_fast2(f32x2 x) {
    f32x2 c1 = {2.3021210f, 2.3021210f}, c2 = {0.10295427f, 0.10295427f};
    f32x2 a = x * __builtin_elementwise_fma(x * x, c2, c1);
    f32x2 E;
    E[0] = EXP2(a[0]); E[1] = EXP2(a[1]);
    f32x2 Ep = E + (f32x2){1.f, 1.f};
    f32x2 r;
    r[0] = __builtin_amdgcn_rcpf(Ep[0]); r[1] = __builtin_amdgcn_rcpf(Ep[1]);
    return __builtin_elementwise_fma(-x, r, x);
}

// unpack u32 of 2 bf16 -> f32x2 {lo, hi}
__device__ __forceinline__ f32x2 unpk_bf2(unsigned int a) {
    f32x2 r;
    r[0] = __uint_as_float(a << 16);
    r[1] = __uint_as_float(a & 0xffff0000u);
    return r;
}

// B fragment from row-major [K][ldn] fp32 weight: r[u] = W[k0+u][n].
__device__ __forceinline__ short8 load_bfrag(const float* __restrict__ w, int k0, int n, int ldn) {
    short8 r;
#pragma unroll
    for (int u = 0; u < 8; ++u)
        r[u] = (short)f2bf(w[(k0 + u) * ldn + n]);
    return r;
}

template<int N1P>
struct SmemMlp {
    unsigned short sS[64 * N1P];     // union: A [64][K+8] then gelu(h) [64][N1P]
    float rstat[64 * 8];
};

// ---------------------------------------------------------------------------
// One MLP-head tile: out = gelu(LN(x@W1+b1)*g+be) @ W2 + b2 for MI*16 rows.
// 4 waves cooperative, fully unrolled, resident breg1. One tile per block.
// ---------------------------------------------------------------------------
template<int K, int N1, int N2, int MI>
__device__ void mlp_tile(SmemMlp<N1 + 8>& sm, const float* __restrict__ x,
                         const float* __restrict__ w1, const float* __restrict__ b1,
                         const float* __restrict__ g, const float* __restrict__ be,
                         const float* __restrict__ w2, const float* __restrict__ b2,
                         float* __restrict__ out, int Nrows, int t) {
    constexpr int R = MI * 16;                 // rows in this tile
    constexpr int KP = K + 8, N1P = N1 + 8;
    constexpr int CPW1 = N1 / 4;
    constexpr int JT1 = CPW1 / 16;
    constexpr int KK1 = K / 32;
    constexpr int KK2 = N1 / 32;
    constexpr int JT2 = N2 / 64;
    constexpr int TPR = 256 / R;               // threads per staged row
    constexpr int FPT = K / TPR;               // floats per thread
    constexpr int F4 = FPT / 4;

    const int tid = threadIdx.x;
    const int wave = tid >> 6, lane = tid & 63;
    const int l15 = lane & 15, quad = lane >> 4;
    const int r0 = t * R;

    {
        int m0 = tid / TPR, pp = tid % TPR;
        int rowg = r0 + m0; if (rowg >= Nrows) rowg = Nrows - 1;
        const float4* src = (const float4*)(x + (long)rowg * K + pp * FPT);
        unsigned short* dst = &sm.sS[m0 * KP + pp * FPT];
#pragma unroll
        for (int u = 0; u < F4; ++u) {
            float4 f = src[u];
            ushort4 h; h.x = f2bf(f.x); h.y = f2bf(f.y); h.z = f2bf(f.z); h.w = f2bf(f.w);
            *(ushort4*)(dst + 4 * u) = h;
        }
    }

    // resident W1 fragments + per-lane params (overlap with staging latency)
    short8 breg1[JT1][KK1];
#pragma unroll
    for (int j = 0; j < JT1; ++j)
#pragma unroll
        for (int kk = 0; kk < KK1; ++kk)
            breg1[j][kk] = load_bfrag(w1, kk * 32 + quad * 8, CPW1 * wave + 16 * j + l15, N1);

    float b1v[JT1], gv[JT1], bev[JT1];
#pragma unroll
    for (int j = 0; j < JT1; ++j) {
        int c = CPW1 * wave + 16 * j + l15;
        b1v[j] = b1[c]; gv[j] = g[c]; bev[j] = be[c];
    }
    float b2v[JT2];
#pragma unroll
    for (int j = 0; j < JT2; ++j) b2v[j] = b2[wave * 16 * JT2 + 16 * j + l15];

    __syncthreads();                           // A ready

    f32x4 acc1[MI][JT1];
#pragma unroll
    for (int i = 0; i < MI; ++i)
#pragma unroll
        for (int j = 0; j < JT1; ++j)
            acc1[i][j] = (f32x4){0.f, 0.f, 0.f, 0.f};

#pragma unroll
    for (int kk = 0; kk < KK1; ++kk) {
        short8 a[MI];
#pragma unroll
        for (int i = 0; i < MI; ++i)
            a[i] = *(const short8*)&sm.sS[(16 * i + l15) * KP + kk * 32 + quad * 8];
#pragma unroll
        for (int i = 0; i < MI; ++i)
#pragma unroll
            for (int j = 0; j < JT1; ++j)
                acc1[i][j] = MFMA(a[i], breg1[j][kk], acc1[i][j]);
    }

#pragma unroll
    for (int i = 0; i < MI; ++i)
#pragma unroll
        for (int r = 0; r < 4; ++r) {
            float s = 0.f, ss = 0.f;
#pragma unroll
            for (int j = 0; j < JT1; ++j) {
                float v = acc1[i][j][r] + b1v[j];
                acc1[i][j][r] = v;
                s += v; ss = __builtin_fmaf(v, v, ss);
            }
            s = rowsum16(s); ss = rowsum16(ss);
            if (l15 == 0) {
                int row = 16 * i + quad * 4 + r;
                *(float2*)&sm.rstat[row * 8 + wave * 2] = make_float2(s, ss);
            }
        }
    __syncthreads();                           // partials ready

#pragma unroll
    for (int i = 0; i < MI; ++i)
#pragma unroll
        for (int r = 0; r < 4; ++r) {
            int row = 16 * i + quad * 4 + r;
            const float4* st = (const float4*)&sm.rstat[row * 8];
            float4 q0 = st[0], q1 = st[1];
            float s  = (q0.x + q0.z) + (q1.x + q1.z);
            float ss = (q0.y + q0.w) + (q1.y + q1.w);
            float mean = s * (1.f / (float)N1);
            float var  = __builtin_fmaf(ss, 1.f / (float)N1, -mean * mean);
            float rstd = __builtin_amdgcn_rsqf(var + 1e-5f);
            float nm = -mean * rstd;
#pragma unroll
            for (int j = 0; j < JT1; ++j) {
                float tt = __builtin_fmaf(acc1[i][j][r], rstd, nm);
                float xn = __builtin_fmaf(tt, gv[j], bev[j]);
                sm.sS[row * N1P + CPW1 * wave + 16 * j + l15] = f2bf(gelu_fast(xn));
            }
        }
    __syncthreads();                           // gelu(h) ready in A-layout

    f32x4 acc2[MI][JT2];
#pragma unroll
    for (int i = 0; i < MI; ++i)
#pragma unroll
        for (int j = 0; j < JT2; ++j)
            acc2[i][j] = (f32x4){0.f, 0.f, 0.f, 0.f};

#pragma unroll
    for (int kk = 0; kk < KK2; ++kk) {
        short8 bf[JT2];
#pragma unroll
        for (int j = 0; j < JT2; ++j)
            bf[j] = load_bfrag(w2, kk * 32 + quad * 8, wave * 16 * JT2 + 16 * j + l15, N2);
        short8 a[MI];
#pragma unroll
        for (int i = 0; i < MI; ++i)
            a[i] = *(const short8*)&sm.sS[(16 * i + l15) * N1P + kk * 32 + quad * 8];
#pragma unroll
        for (int i = 0; i < MI; ++i)
#pragma unroll
            for (int j = 0; j < JT2; ++j)
                acc2[i][j] = MFMA(a[i], bf[j], acc2[i][j]);
    }

#pragma unroll
    for (int i = 0; i < MI; ++i)
#pragma unroll
        for (int r = 0; r < 4; ++r) {
            int rowg = r0 + 16 * i + quad * 4 + r;
            if (rowg < Nrows) {
#pragma unroll
                for (int j = 0; j < JT2; ++j)
                    out[(long)rowg * N2 + wave * 16 * JT2 + 16 * j + l15] = acc2[i][j][r] + b2v[j];
            }
        }
}

// ---------------------------------------------------------------------------
// One proj tile-plane: P = x @ W1half (+ b1 for A-plane), bf16 [N][256] in the
// PERMUTED column layout (storage slot wave*64+l15*4+j holds logical col
// wave*64+16*j+l15) -> one dwordx2 store per (i,r), fully contiguous.
// ---------------------------------------------------------------------------
__device__ void proj_tile(unsigned short* sX /*64*72*/, const float* __restrict__ x,
                          const float* __restrict__ w1, const float* __restrict__ b1,
                          unsigned short* __restrict__ P, int N, int tile, int isB) {
    constexpr int KP = 72;                     // 144B stride -> 2-way alias (free)
    const int tid = threadIdx.x;
    const int wave = tid >> 6, lane = tid & 63;
    const int l15 = lane & 15, quad = lane >> 4;
    const int r0 = tile * 64;

    {
        int m0 = tid >> 2, pp = tid & 3;       // 4 threads/row, 16 floats each
        int rowg = r0 + m0; if (rowg >= N) rowg = N - 1;
        const float4* src = (const float4*)(x + (long)rowg * 64 + pp * 16);
        unsigned short* dst = &sX[m0 * KP + pp * 16];
#pragma unroll
        for (int u = 0; u < 4; ++u) {
            float4 f = src[u];
            ushort4 h; h.x = f2bf(f.x); h.y = f2bf(f.y); h.z = f2bf(f.z); h.w = f2bf(f.w);
            *(ushort4*)(dst + 4 * u) = h;
        }
    }

    short8 breg[4][2];
#pragma unroll
    for (int j = 0; j < 4; ++j)
#pragma unroll
        for (int kk = 0; kk < 2; ++kk)
            breg[j][kk] = load_bfrag(w1, isB * 64 + kk * 32 + quad * 8, wave * 64 + 16 * j + l15, 256);

    float b1v[4];
#pragma unroll
    for (int j = 0; j < 4; ++j)
        b1v[j] = isB ? 0.f : b1[wave * 64 + 16 * j + l15];

    __syncthreads();

    f32x4 acc[4][4];
#pragma unroll
    for (int i = 0; i < 4; ++i)
#pragma unroll
        for (int j = 0; j < 4; ++j)
            acc[i][j] = (f32x4){0.f, 0.f, 0.f, 0.f};

#pragma unroll
    for (int kk = 0; kk < 2; ++kk) {
        short8 a[4];
#pragma unroll
        for (int i = 0; i < 4; ++i)
            a[i] = *(const short8*)&sX[(16 * i + l15) * KP + kk * 32 + quad * 8];
#pragma unroll
        for (int i = 0; i < 4; ++i)
#pragma unroll
            for (int j = 0; j < 4; ++j)
                acc[i][j] = MFMA(a[i], breg[j][kk], acc[i][j]);
    }

#pragma unroll
    for (int i = 0; i < 4; ++i)
#pragma unroll
        for (int r = 0; r < 4; ++r) {
            int rowg = r0 + 16 * i + quad * 4 + r;     // C/D: row = quad*4+reg
            if (rowg < N) {
                uint2 d;
                d.x = cvt_pk_bf16(acc[i][0][r] + b1v[0], acc[i][1][r] + b1v[1]);
                d.y = cvt_pk_bf16(acc[i][2][r] + b1v[2], acc[i][3][r] + b1v[3]);
                *(uint2*)(P + (long)rowg * 256 + wave * 64 + l15 * 4) = d;
            }
        }
}

// ---------------------------------------------------------------------------
// Edge role: per wave 4 edges (one per 16-lane quad), 16 cols/lane, f32x2
// packed math (v_pk_add/v_pk_fma) for the column loops. 2-deep SW pipeline.
// ---------------------------------------------------------------------------
__device__ __forceinline__ int clamp_e(long v, int E) {
    return v < (long)E ? (int)v : E - 1;
}

__device__ void edge_role2(const unsigned short* __restrict__ Pa,
                           const unsigned short* __restrict__ Pb,
                           const int* __restrict__ ei,
                           const float* __restrict__ g, const float* __restrict__ be,
                           const float* __restrict__ w2, const float* __restrict__ b2,
                           float* __restrict__ out, int E, int ebid, int nebk) {
    const int tid = threadIdx.x;
    const int lane = tid & 63;
    const int quad = lane >> 4, l15 = lane & 15;

    // per-lane params for storage slots l15*16+u under the proj permutation:
    // logical col = (l15>>2)*64 + (u&3)*16 + (l15&3)*4 + (u>>2); packed pairs
    // (2k, 2k+1) to match unpk_bf2's {lo,hi}.
    f32x2 gv2[8], bev2[8], w2v2[8];
#pragma unroll
    for (int k = 0; k < 8; ++k) {
#pragma unroll
        for (int h = 0; h < 2; ++h) {
            int u = 2 * k + h;
            int c = ((l15 >> 2) << 6) + ((u & 3) << 4) + ((l15 & 3) << 2) + (u >> 2);
            gv2[k][h] = g[c]; bev2[k][h] = be[c]; w2v2[k][h] = w2[c];
        }
    }
    const float b2v = b2[0];

    const int wid = ebid * 4 + (tid >> 6);
    const long stride = (long)nebk * 16L;      // nebk blocks * 4 waves * 4 edges
    long base = (long)wid * 4;
    if (base >= E) return;

    // pipeline prologue: rows for iter 0, indices for iter 1
    int ir1, ic1;
    uint4 cA0, cA1, cB0, cB1;
    {
        int e0 = clamp_e(base + quad, E);
        int r = ei[e0], c = ei[E + e0];
        const uint4* pa = (const uint4*)(Pa + (long)r * 256 + l15 * 16);
        const uint4* pb = (const uint4*)(Pb + (long)c * 256 + l15 * 16);
        cA0 = pa[0]; cA1 = pa[1]; cB0 = pb[0]; cB1 = pb[1];
        int e1 = clamp_e(base + stride + quad, E);
        ir1 = ei[e1]; ic1 = ei[E + e1];
    }

    for (; base < E; base += stride) {
        int e2 = clamp_e(base + 2 * stride + quad, E);
        int ir2 = ei[e2];
        int ic2 = ei[E + e2];
        const uint4* pa = (const uint4*)(Pa + (long)ir1 * 256 + l15 * 16);
        const uint4* pb = (const uint4*)(Pb + (long)ic1 * 256 + l15 * 16);
        uint4 nA0 = pa[0], nA1 = pa[1], nB0 = pb[0], nB1 = pb[1];

        unsigned int av[8] = {cA0.x, cA0.y, cA0.z, cA0.w, cA1.x, cA1.y, cA1.z, cA1.w};
        unsigned int bv[8] = {cB0.x, cB0.y, cB0.z, cB0.w, cB1.x, cB1.y, cB1.z, cB1.w};

        f32x2 h2[8];
        f32x2 s2 = {0.f, 0.f}, ss2 = {0.f, 0.f};
#pragma unroll
        for (int k = 0; k < 8; ++k) {
            h2[k] = unpk_bf2(av[k]) + unpk_bf2(bv[k]);
            s2 = s2 + h2[k];
            ss2 = __builtin_elementwise_fma(h2[k], h2[k], ss2);
        }
        float s = s2[0] + s2[1], ss = ss2[0] + ss2[1];
        s = rowsum16(s); ss = rowsum16(ss);

        float mean = s * (1.f / 256.f);
        float var  = __builtin_fmaf(ss, 1.f / 256.f, -mean * mean);
        float rstd = __builtin_amdgcn_rsqf(var + 1e-5f);
        float nm = -mean * rstd;
        f32x2 rstd2 = {rstd, rstd}, nm2 = {nm, nm};

        f32x2 spp2 = {0.f, 0.f};
#pragma unroll
        for (int k = 0; k < 8; ++k) {
            f32x2 tt = __builtin_elementwise_fma(h2[k], rstd2, nm2);
            f32x2 xn = __builtin_elementwise_fma(tt, gv2[k], bev2[k]);
            spp2 = __builtin_elementwise_fma(gelu_fast2(xn), w2v2[k], spp2);
        }
        float spp = rowsum16(spp2[0] + spp2[1]);
        long eL = base + quad;
        if (l15 == 0 && eL < E) out[eL] = spp + b2v;

        cA0 = nA0; cA1 = nA1; cB0 = nB0; cB1 = nB1;
        ir1 = ir2; ic1 = ic2;
    }
}

// =============================== R5 kernels =================================
union SmemPrep {
    unsigned short sX[64 * 72];
    SmemMlp<136> a;            // FR: N1=128
    SmemMlp<264> b;            // PH: N1=256 (35840 B, the max)
};

// prep: ONE dispatch for proj + both heads (all independent one-tile blocks).
// Block order: PH tiles (longest) first, then FR, then proj planes.
__global__ __launch_bounds__(256, 3)
void prep_kernel(const float* __restrict__ x,
                 const float* __restrict__ sp_w1, const float* __restrict__ sp_b1,
                 const float* __restrict__ fr_w1, const float* __restrict__ fr_b1,
                 const float* __restrict__ fr_g, const float* __restrict__ fr_be,
                 const float* __restrict__ fr_w2, const float* __restrict__ fr_b2,
                 const float* __restrict__ ph_w1, const float* __restrict__ ph_b1,
                 const float* __restrict__ ph_g, const float* __restrict__ ph_be,
                 const float* __restrict__ ph_w2, const float* __restrict__ ph_b2,
                 unsigned short* __restrict__ Pa, unsigned short* __restrict__ Pb,
                 float* __restrict__ out_rec, float* __restrict__ out_proj,
                 int N, int ntN, int nFR, int nPH) {
    __shared__ SmemPrep sm;
    const int b = blockIdx.x;
    if (b < nPH) {
        mlp_tile<64, 256, 128, 2>(sm.b, x, ph_w1, ph_b1, ph_g, ph_be, ph_w2, ph_b2,
                                  out_proj, N, b);
    } else if (b < nPH + nFR) {
        mlp_tile<64, 128, 64, 4>(sm.a, x, fr_w1, fr_b1, fr_g, fr_be, fr_w2, fr_b2,
                                 out_rec, N, b - nPH);
    } else {
        int q = b - nPH - nFR;
        int isB = q >= ntN;
        int tile = isB ? q - ntN : q;
        proj_tile(sm.sX, x, sp_w1, sp_b1, isB ? Pb : Pa, N, tile, isB);
    }
}

// edge: standalone, low-VGPR, no LDS -- the proven >90%-VALUBusy config.
__global__ __launch_bounds__(256)
void edge_stream(const unsigned short* __restrict__ Pa, const unsigned short* __restrict__ Pb,
                 const int* __restrict__ ei,
                 const float* __restrict__ g, const float* __restrict__ be,
                 const float* __restrict__ w2, const float* __restrict__ b2,
                 float* __restrict__ out, int E) {
    edge_role2(Pa, Pb, ei, g, be, w2, b2, out, E, blockIdx.x, gridDim.x);
}

// ======================= fallback (ws too small) ============================
struct SmemEdge {
    unsigned short sA[2][32 * 136];
    float rstat[32 * 8];
    float spL[32 * 4];
};
union SmemU {
    SmemEdge e;
    SmemMlp<136> a;
    SmemMlp<264> b;
};

__device__ void edge_role(SmemEdge& sm, const float* __restrict__ x, const int* __restrict__ ei,
                          const float* __restrict__ w1, const float* __restrict__ b1,
                          const float* __restrict__ g, const float* __restrict__ be,
                          const float* __restrict__ w2, const float* __restrict__ b2,
                          float* __restrict__ out, int E, int bid, int nblocks) {
    constexpr int KP = 136;
    const int tid = threadIdx.x;
    const int cw = tid >> 6, lane = tid & 63;
    const int l15 = lane & 15, quad = lane >> 4;

    short8 breg[4][4];
#pragma unroll
    for (int j = 0; j < 4; ++j)
#pragma unroll
        for (int kk = 0; kk < 4; ++kk)
            breg[j][kk] = load_bfrag(w1, kk * 32 + quad * 8, cw * 64 + 16 * j + l15, 256);

    float b1v[4], gv[4], bev[4], w2v[4];
#pragma unroll
    for (int j = 0; j < 4; ++j) {
        int c = cw * 64 + 16 * j + l15;
        b1v[j] = b1[c]; gv[j] = g[c]; bev[j] = be[c]; w2v[j] = w2[c];
    }
    const float b2v = b2[0];

    const int ntiles = (E + 31) >> 5;
    const int eLoc = tid >> 3, p = tid & 7;
    const int node = p >> 2, foff = (p & 3) * 16;

    float4 pf[4];
    auto issue = [&](int t) {
        int e = t * 32 + eLoc; if (e >= E) e = E - 1;
        int idx = ei[node * E + e];
        const float4* src = (const float4*)(x + (long)idx * 64 + foff);
#pragma unroll
        for (int u = 0; u < 4; ++u) pf[u] = src[u];
    };
    auto stage = [&](int buf) {
        unsigned short* dst = &sm.sA[buf][eLoc * KP + node * 64 + foff];
#pragma unroll
        for (int u = 0; u < 4; ++u) {
            ushort4 h;
            h.x = f2bf(pf[u].x); h.y = f2bf(pf[u].y);
            h.z = f2bf(pf[u].z); h.w = f2bf(pf[u].w);
            *(ushort4*)(dst + 4 * u) = h;
        }
    };

    int t = bid;
    if (t >= ntiles) return;
    issue(t); stage(0);
    if (t + nblocks < ntiles) issue(t + nblocks);
    __syncthreads();
    int cur = 0;

    for (; t < ntiles; t += nblocks) {
        f32x4 acc[2][4];
#pragma unroll
        for (int i = 0; i < 2; ++i)
#pragma unroll
            for (int j = 0; j < 4; ++j)
                acc[i][j] = (f32x4){0.f, 0.f, 0.f, 0.f};

#pragma unroll
        for (int kk = 0; kk < 4; ++kk) {
            short8 a[2];
#pragma unroll
            for (int i = 0; i < 2; ++i)
                a[i] = *(const short8*)&sm.sA[cur][(16 * i + l15) * KP + kk * 32 + quad * 8];
#pragma unroll
            for (int i = 0; i < 2; ++i)
#pragma unroll
                for (int j = 0; j < 4; ++j)
                    acc[i][j] = MFMA(a[i], breg[j][kk], acc[i][j]);
        }

        if (t + nblocks < ntiles) {
            stage(cur ^ 1);
            if (t + 2 * nblocks < ntiles) issue(t + 2 * nblocks);
        }

#pragma unroll
        for (int i = 0; i < 2; ++i)
#pragma unroll
            for (int r = 0; r < 4; ++r) {
                float v0 = acc[i][0][r] + b1v[0];
                float v1 = acc[i][1][r] + b1v[1];
                float v2 = acc[i][2][r] + b1v[2];
                float v3 = acc[i][3][r] + b1v[3];
                acc[i][0][r] = v0; acc[i][1][r] = v1; acc[i][2][r] = v2; acc[i][3][r] = v3;
                float s  = (v0 + v1) + (v2 + v3);
                float ss = __builtin_fmaf(v0, v0, __builtin_fmaf(v1, v1,
                           __builtin_fmaf(v2, v2, v3 * v3)));
                s = rowsum16(s); ss = rowsum16(ss);
                if (l15 == 0) {
                    int row = 16 * i + quad * 4 + r;
                    *(float2*)&sm.rstat[row * 8 + cw * 2] = make_float2(s, ss);
                }
            }
        __syncthreads();

#pragma unroll
        for (int i = 0; i < 2; ++i)
#pragma unroll
            for (int r = 0; r < 4; ++r) {
                int row = 16 * i + quad * 4 + r;
                const float4* st = (const float4*)&sm.rstat[row * 8];
                float4 q0 = st[0], q1 = st[1];
                float s  = (q0.x + q0.z) + (q1.x + q1.z);
                float ss = (q0.y + q0.w) + (q1.y + q1.w);
                float mean = s * (1.f / 256.f);
                float var  = __builtin_fmaf(ss, 1.f / 256.f, -mean * mean);
                float rstd = __builtin_amdgcn_rsqf(var + 1e-5f);
                float nm = -mean * rstd;
                float spp = 0.f;
#pragma unroll
                for (int j = 0; j < 4; ++j) {
                    float tt = __builtin_fmaf(acc[i][j][r], rstd, nm);
                    float xn = __builtin_fmaf(tt, gv[j], bev[j]);
                    spp = __builtin_fmaf(gelu_fast(xn), w2v[j], spp);
                }
                spp = rowsum16(spp);
                if (l15 == 0) sm.spL[row * 4 + cw] = spp;
            }
        __syncthreads();

        if (tid < 32) {
            int e = t * 32 + tid;
            if (e < E) {
                const float4* sp = (const float4*)&sm.spL[tid * 4];
                float4 u0 = sp[0];
                out[e] = ((u0.x + u0.y) + (u0.z + u0.w)) + b2v;
            }
        }
        cur ^= 1;
    }
}

__global__ __launch_bounds__(256, 3)
void fused_all(const float* __restrict__ x, const int* __restrict__ ei,
               const float* __restrict__ sp_w1, const float* __restrict__ sp_b1,
               const float* __restrict__ sp_g, const float* __restrict__ sp_be,
               const float* __restrict__ sp_w2, const float* __restrict__ sp_b2,
               const float* __restrict__ fr_w1, const float* __restrict__ fr_b1,
               const float* __restrict__ fr_g, const float* __restrict__ fr_be,
               const float* __restrict__ fr_w2, const float* __restrict__ fr_b2,
               const float* __restrict__ ph_w1, const float* __restrict__ ph_b1,
               const float* __restrict__ ph_g, const float* __restrict__ ph_be,
               const float* __restrict__ ph_w2, const float* __restrict__ ph_b2,
               float* __restrict__ out_sp, float* __restrict__ out_rec,
               float* __restrict__ out_proj, int N, int E) {
    __shared__ SmemU sm;
    const int b = blockIdx.x;
    if (b < 128) {
        for (int tt = b; tt < (N + 63) / 64; tt += 128) {
            __syncthreads();                   // smem reuse guard between tiles
            mlp_tile<64, 128, 64, 4>(sm.a, x, fr_w1, fr_b1, fr_g, fr_be, fr_w2, fr_b2,
                                     out_rec, N, tt);
        }
    } else if (b < 256) {
        for (int tt = b - 128; tt < (N + 31) / 32; tt += 128) {
            __syncthreads();                   // smem reuse guard between tiles
            mlp_tile<64, 256, 128, 2>(sm.b, x, ph_w1, ph_b1, ph_g, ph_be, ph_w2, ph_b2,
                                      out_proj, N, tt);
        }
    } else {
        edge_role(sm.e, x, ei, sp_w1, sp_b1, sp_g, sp_be, sp_w2, sp_b2,
                  out_sp, E, b - 256, 1024);
    }
}
// ===========================================================================

extern "C" void kernel_launch(void* const* d_in, const int* in_sizes, int n_in,
                              void* d_out, int out_size, void* d_ws, size_t ws_size,
                              hipStream_t stream) {
    const float* x     = (const float*)d_in[0];
    const int*   ei    = (const int*)d_in[1];
    const float* sp_w1 = (const float*)d_in[2];
    const float* sp_b1 = (const float*)d_in[3];
    const float* sp_g  = (const float*)d_in[4];
    const float* sp_be = (const float*)d_in[5];
    const float* sp_w2 = (const float*)d_in[6];
    const float* sp_b2 = (const float*)d_in[7];
    const float* fr_w1 = (const float*)d_in[8];
    const float* fr_b1 = (const float*)d_in[9];
    const float* fr_g  = (const float*)d_in[10];
    const float* fr_be = (const float*)d_in[11];
    const float* fr_w2 = (const float*)d_in[12];
    const float* fr_b2 = (const float*)d_in[13];
    const float* ph_w1 = (const float*)d_in[14];
    const float* ph_b1 = (const float*)d_in[15];
    const float* ph_g  = (const float*)d_in[16];
    const float* ph_be = (const float*)d_in[17];
    const float* ph_w2 = (const float*)d_in[18];
    const float* ph_b2 = (const float*)d_in[19];

    const int N = in_sizes[0] / 64;
    const int E = in_sizes[1] / 2;

    float* out_sp   = (float*)d_out;
    float* out_rec  = out_sp + E;
    float* out_proj = out_rec + (size_t)N * 64;

    const size_t needed = 2ull * (size_t)N * 256 * sizeof(unsigned short);
    if (ws_size >= needed) {
        unsigned short* Pa = (unsigned short*)d_ws;
        unsigned short* Pb = Pa + (size_t)N * 256;
        const int ntN = (N + 63) / 64;         // proj tiles per plane
        const int nFR = (N + 63) / 64;         // FR tiles (64-row)
        const int nPH = (N + 31) / 32;         // PH tiles (32-row)

        prep_kernel<<<dim3(nPH + nFR + 2 * ntN), dim3(256), 0, stream>>>(
            x, sp_w1, sp_b1,
            fr_w1, fr_b1, fr_g, fr_be, fr_w2, fr_b2,
            ph_w1, ph_b1, ph_g, ph_be, ph_w2, ph_b2,
            Pa, Pb, out_rec, out_proj, N, ntN, nFR, nPH);

        edge_stream<<<dim3(2048), dim3(256), 0, stream>>>(
            Pa, Pb, ei, sp_g, sp_be, sp_w2, sp_b2, out_sp, E);
    } else {
        fused_all<<<dim3(1280), dim3(256), 0, stream>>>(
            x, ei, sp_w1, sp_b1, sp_g, sp_be, sp_w2, sp_b2,
            fr_w1, fr_b1, fr_g, fr_be, fr_w2, fr_b2,
            ph_w1, ph_b1, ph_g, ph_be, ph_w2, ph_b2,
            out_sp, out_rec, out_proj, N, E);
    }
}